// Round 4
// baseline (419.401 us; speedup 1.0000x reference)
//
#include <hip/hip_runtime.h>
#include <stdint.h>

typedef __bf16          bf16x8  __attribute__((ext_vector_type(8)));
typedef unsigned short  ushort8 __attribute__((ext_vector_type(8)));
typedef float           f32x4   __attribute__((ext_vector_type(4)));
typedef unsigned int    u32x2   __attribute__((ext_vector_type(2)));

__device__ __forceinline__ unsigned short f2bf(float f) {
    unsigned int u = __float_as_uint(f);
    return (unsigned short)((u + 0x7FFFu + ((u >> 16) & 1u)) >> 16);
}
__device__ __forceinline__ unsigned int pk2(float lo, float hi) {
    return ((unsigned int)f2bf(hi) << 16) | (unsigned int)f2bf(lo);
}

#define W1_SLOTS (12*16*64)
#define W2_SLOTS (8*16*64)

// Repack w1 (384x256) / w2 (256x256) fp32 -> bf16 MFMA A-operand fragments,
// NATURAL k-order for both: slot (s,t,l), elem j = w[k = s*32 + (l>>4)*8 + j][n = t*16 + (l&15)].
__global__ void prep_weights(const float* __restrict__ w1, const float* __restrict__ w2,
                             unsigned short* __restrict__ w1f, unsigned short* __restrict__ w2f) {
    int id = blockIdx.x * 256 + threadIdx.x;
    if (id >= W1_SLOTS + W2_SLOTS) return;
    const float* src; unsigned short* dst; int slot;
    if (id < W1_SLOTS) { src = w1; dst = w1f; slot = id; }
    else               { src = w2; dst = w2f; slot = id - W1_SLOTS; }
    int l  = slot & 63;
    int t  = (slot >> 6) & 15;
    int s  = slot >> 10;
    int k0 = s*32 + ((l >> 4) << 3);
    int n  = t*16 + (l & 15);
    unsigned short* d = dst + (size_t)slot * 8;
    #pragma unroll
    for (int j = 0; j < 8; ++j) d[j] = f2bf(src[(size_t)(k0 + j) * 256 + n]);
}

// Feature-split block: 64 rows/block, wave w owns features [64w, 64w+64) for ALL
// rows -> acc[4][4] = 64 regs (was 128+64: the round-3 spill). Weights read
// per-wave direct from L2 (each wave reads ONLY its 80KB slice). Embeddings
// produced once (wave w makes step 4p+w, lane=row) and shared via 16KB h0
// fragment LDS reused over 3 phases; h1 crosses waves via 32KB slot-layout LDS.
// 6 barriers/block. Swapped-operand MFMA (D = W^T h^T) as validated in r2/r3.
__global__ __launch_bounds__(256, 3) void courier_main(
    const float* __restrict__ xy,   const float* __restrict__ tin,
    const float* __restrict__ w_sx, const float* __restrict__ b_sx,
    const float* __restrict__ w_cx, const float* __restrict__ b_cx,
    const float* __restrict__ w_sy, const float* __restrict__ b_sy,
    const float* __restrict__ w_cy, const float* __restrict__ b_cy,
    const float* __restrict__ w_t,  const float* __restrict__ b_t,
    const unsigned short* __restrict__ w1f, const float* __restrict__ b1,
    const unsigned short* __restrict__ w2f, const float* __restrict__ b2,
    float* __restrict__ out)
{
    __shared__ __align__(16) unsigned short h0s[4*4*64*8];   // 16 KB: [sp][mi][lane][8]
    __shared__ __align__(16) unsigned short h1s[8*4*64*8];   // 32 KB: [s][mi][lane][8]

    const int tid  = threadIdx.x;
    const int lane = tid & 63;
    const int wv   = tid >> 6;       // wave id = feature slice AND produced step-in-phase
    const int l15  = lane & 15;
    const int lq   = lane >> 4;
    const int rowblk = blockIdx.x * 64;

    // coords for embedding production: this thread produces row = lane
    const float px = xy[(size_t)(rowblk + lane)*2 + 0];
    const float py = xy[(size_t)(rowblk + lane)*2 + 1];
    const float pt = tin[rowblk + lane];

    const bf16x8* gw1 = (const bf16x8*)w1f;
    const bf16x8* gw2 = (const bf16x8*)w2f;

    f32x4 acc[4][4];                 // [tt][mi]
    #pragma unroll
    for (int a=0;a<4;++a)
      #pragma unroll
      for (int b=0;b<4;++b)
        #pragma unroll
        for (int i=0;i<4;++i) acc[a][b][i] = 0.0f;

    bf16x8 wc[4], wn[4];

    // =================== layer 1: 3 phases x 4 k-steps ========================
    #pragma unroll
    for (int p = 0; p < 3; ++p) {
        if (p) __syncthreads();      // phase p-1 consumers done before h0 overwrite

        // ---- produce h0 for step s = 4p + wv, rows = lane (all 64 rows) ------
        {
            const int s = 4*p + wv;
            const float* wp; const float* bp; float c; int o;
            bool iscos = false, istime = false;
            if (s < 8) {
                const int seg = s >> 1;          // 0:sinx 1:cosx 2:siny 3:cosy
                wp = (seg==0)?w_sx:(seg==1)?w_cx:(seg==2)?w_sy:w_cy;
                bp = (seg==0)?b_sx:(seg==1)?b_cx:(seg==2)?b_sy:b_cy;
                c  = (seg<2)?px:py;
                iscos = (s & 2) != 0;
                o  = (s & 1) << 5;
            } else {
                wp = w_t; bp = b_t; c = pt; istime = true;
                o  = (s - 8) << 5;
            }
            const int mi = lane >> 4;            // row>>4 (row = lane)
            #pragma unroll
            for (int i = 0; i < 4; ++i) {        // i = lq' (k sub-group of 8)
                f32x4 wa = *(const f32x4*)(wp + o + 8*i);
                f32x4 wb = *(const f32x4*)(wp + o + 8*i + 4);
                f32x4 ba = *(const f32x4*)(bp + o + 8*i);
                f32x4 bb = *(const f32x4*)(bp + o + 8*i + 4);
                ushort8 u;
                #pragma unroll
                for (int j = 0; j < 8; ++j) {
                    float wvv = (j<4)?wa[j]:wb[j-4];
                    float bvv = (j<4)?ba[j]:bb[j-4];
                    float th = c*wvv + bvv;
                    float v;
                    if (istime)      v = fmaxf(th, 0.01f*th);
                    else if (iscos)  v = __cosf(th);
                    else             v = __sinf(th);
                    u[j] = f2bf(v);
                }
                // slot (sp=wv, mi, lane' = i*16 + (row&15))
                *(bf16x8*)&h0s[ (((wv*4 + mi)*64) + i*16 + l15) * 8 ] =
                    __builtin_bit_cast(bf16x8, u);
            }
        }

        // issue this phase's first weight frags before the barrier
        #pragma unroll
        for (int tt=0; tt<4; ++tt)
            wc[tt] = gw1[(size_t)(((4*p)*16 + 4*wv + tt)*64 + lane)];

        __syncthreads();             // h0 ready

        // ---- consume 4 steps -------------------------------------------------
        #pragma unroll
        for (int sp = 0; sp < 4; ++sp) {
            const int s = 4*p + sp;
            // prefetch next step's weight frags (layer-2 step 0 at the very end)
            if (s < 11) {
                #pragma unroll
                for (int tt=0; tt<4; ++tt)
                    wn[tt] = gw1[(size_t)(((s+1)*16 + 4*wv + tt)*64 + lane)];
            } else {
                #pragma unroll
                for (int tt=0; tt<4; ++tt)
                    wn[tt] = gw2[(size_t)((4*wv + tt)*64 + lane)];
            }
            bf16x8 mf[4];
            #pragma unroll
            for (int mi=0; mi<4; ++mi)
                mf[mi] = *(const bf16x8*)&h0s[ ((sp*4 + mi)*64 + lane) * 8 ];
            #pragma unroll
            for (int tt=0; tt<4; ++tt)
                #pragma unroll
                for (int mi=0; mi<4; ++mi)
                    acc[tt][mi] = __builtin_amdgcn_mfma_f32_16x16x32_bf16(
                                      wc[tt], mf[mi], acc[tt][mi], 0,0,0);
            #pragma unroll
            for (int tt=0; tt<4; ++tt) wc[tt] = wn[tt];
        }
    }

    // =================== epilogue 1: h1 -> slot-layout LDS ====================
    // lane holds h1[row = 16mi + l15][f = 64wv + 16tt + 4lq + r].
    // pair (f,f+1) -> slot s2 = 2wv + (tt>>1), lane' = (2(tt&1)+(lq>>1))*16 + l15,
    // dwords 2(lq&1)+{0,1} -> one aligned b64 write per (tt,mi).
    #pragma unroll
    for (int tt=0; tt<4; ++tt) {
        const f32x4 bv = *(const f32x4*)(b1 + 64*wv + 16*tt + 4*lq);
        const int s2   = 2*wv + (tt >> 1);
        const int lphi = 2*(tt & 1) + (lq >> 1);
        #pragma unroll
        for (int mi=0; mi<4; ++mi) {
            float v0 = acc[tt][mi][0] + bv[0]; v0 = fmaxf(v0, 0.01f*v0);
            float v1 = acc[tt][mi][1] + bv[1]; v1 = fmaxf(v1, 0.01f*v1);
            float v2 = acc[tt][mi][2] + bv[2]; v2 = fmaxf(v2, 0.01f*v2);
            float v3 = acc[tt][mi][3] + bv[3]; v3 = fmaxf(v3, 0.01f*v3);
            u32x2 dd; dd[0] = pk2(v0, v1); dd[1] = pk2(v2, v3);
            unsigned int* base =
                (unsigned int*)&h1s[ ((s2*4 + mi)*64 + lphi*16 + l15) * 8 ];
            *(u32x2*)&base[2*(lq & 1)] = dd;
        }
    }

    #pragma unroll
    for (int a=0;a<4;++a)
      #pragma unroll
      for (int b=0;b<4;++b)
        #pragma unroll
        for (int i=0;i<4;++i) acc[a][b][i] = 0.0f;

    __syncthreads();                 // h1 ready (cross-wave)

    // =================== layer 2: 8 k-steps, m-frags from h1 slots ============
    #pragma unroll
    for (int s = 0; s < 8; ++s) {
        if (s < 7) {
            #pragma unroll
            for (int tt=0; tt<4; ++tt)
                wn[tt] = gw2[(size_t)(((s+1)*16 + 4*wv + tt)*64 + lane)];
        }
        bf16x8 mf[4];
        #pragma unroll
        for (int mi=0; mi<4; ++mi)
            mf[mi] = *(const bf16x8*)&h1s[ ((s*4 + mi)*64 + lane) * 8 ];
        #pragma unroll
        for (int tt=0; tt<4; ++tt)
            #pragma unroll
            for (int mi=0; mi<4; ++mi)
                acc[tt][mi] = __builtin_amdgcn_mfma_f32_16x16x32_bf16(
                                  wc[tt], mf[mi], acc[tt][mi], 0,0,0);
        #pragma unroll
        for (int tt=0; tt<4; ++tt) wc[tt] = wn[tt];
    }

    // =================== epilogue 2: out = leaky(acc+b2) ======================
    #pragma unroll
    for (int tt=0; tt<4; ++tt) {
        const f32x4 bv = *(const f32x4*)(b2 + 64*wv + 16*tt + 4*lq);
        #pragma unroll
        for (int mi=0; mi<4; ++mi) {
            f32x4 o;
            #pragma unroll
            for (int r=0; r<4; ++r) {
                float v = acc[tt][mi][r] + bv[r];
                o[r] = fmaxf(v, 0.01f*v);
            }
            const int row = rowblk + 16*mi + l15;
            *(f32x4*)(out + (size_t)row*256 + 64*wv + 16*tt + 4*lq) = o;
        }
    }
}

extern "C" void kernel_launch(void* const* d_in, const int* in_sizes, int n_in,
                              void* d_out, int out_size, void* d_ws, size_t ws_size,
                              hipStream_t stream) {
    const float* xy   = (const float*)d_in[0];
    const float* tin  = (const float*)d_in[1];
    const float* w_sx = (const float*)d_in[2];
    const float* b_sx = (const float*)d_in[3];
    const float* w_cx = (const float*)d_in[4];
    const float* b_cx = (const float*)d_in[5];
    const float* w_sy = (const float*)d_in[6];
    const float* b_sy = (const float*)d_in[7];
    const float* w_cy = (const float*)d_in[8];
    const float* b_cy = (const float*)d_in[9];
    const float* w_t  = (const float*)d_in[10];
    const float* b_t  = (const float*)d_in[11];
    const float* w1   = (const float*)d_in[12];
    const float* b1   = (const float*)d_in[13];
    const float* w2   = (const float*)d_in[14];
    const float* b2   = (const float*)d_in[15];

    unsigned short* w1f = (unsigned short*)d_ws;        // 196608 B
    unsigned short* w2f = w1f + (size_t)W1_SLOTS * 8;   // 131072 B

    prep_weights<<<(W1_SLOTS + W2_SLOTS + 255)/256, 256, 0, stream>>>(w1, w2, w1f, w2f);
    courier_main<<<262144/64, 256, 0, stream>>>(xy, tin, w_sx,b_sx,w_cx,b_cx,
                                                w_sy,b_sy,w_cy,b_cy,w_t,b_t,
                                                w1f, b1, w2f, b2, (float*)d_out);
}